// Round 1
// baseline (11833.155 us; speedup 1.0000x reference)
//
#include <hip/hip_runtime.h>
#include <math.h>

// ---------------------------------------------------------------------------
// SimpleTransformerLM forward, fp32 baseline (round 1: correctness first).
// B=2, S=1024, D=1024, H=16, DK=64, L=4, F=4096, V=32000.
// Plan: embed+PE -> per layer {QKV gemm, per-row attention, O proj, add+LN,
// FF1(+ReLU), FF2, add+LN} -> final LN -> head gemm into d_out.
// All GEMMs are C[M,N] = A[M,K] @ W[N,K]^T + bias  (weights are [out,in]).
// ---------------------------------------------------------------------------

namespace {
constexpr int kV  = 32000;
constexpr int kD  = 1024;
constexpr int kH  = 16;
constexpr int kL  = 4;
constexpr int kF  = 4096;
constexpr int kS  = 1024;
constexpr int kB  = 2;
constexpr int kDK = 64;
constexpr int kM  = kB * kS;   // 2048 rows
constexpr float kEps   = 1e-5f;
constexpr float kScale = 0.125f;   // 1/sqrt(DK)
}

// ---- block reductions (blockDim.x == 256 -> 4 waves of 64) ----------------
__device__ __forceinline__ float block_sum256(float v, float* scratch) {
#pragma unroll
  for (int off = 32; off > 0; off >>= 1) v += __shfl_down(v, off, 64);
  const int wid  = threadIdx.x >> 6;
  const int lane = threadIdx.x & 63;
  __syncthreads();                 // protect scratch reuse across calls
  if (lane == 0) scratch[wid] = v;
  __syncthreads();
  return scratch[0] + scratch[1] + scratch[2] + scratch[3];
}

__device__ __forceinline__ float block_max256(float v, float* scratch) {
#pragma unroll
  for (int off = 32; off > 0; off >>= 1) v = fmaxf(v, __shfl_down(v, off, 64));
  const int wid  = threadIdx.x >> 6;
  const int lane = threadIdx.x & 63;
  __syncthreads();
  if (lane == 0) scratch[wid] = v;
  __syncthreads();
  return fmaxf(fmaxf(scratch[0], scratch[1]), fmaxf(scratch[2], scratch[3]));
}

// ---- embedding + positional encoding --------------------------------------
__global__ __launch_bounds__(256) void embed_pe_kernel(
    const int* __restrict__ ids, const float* __restrict__ embed,
    float* __restrict__ x) {
  const int row = blockIdx.x;           // b*kS + s
  const int s   = row & (kS - 1);
  const int id  = ids[row];
  const float* erow = embed + (size_t)id * kD;
  float* xrow = x + (size_t)row * kD;
#pragma unroll
  for (int i = 0; i < kD / 256; ++i) {
    const int d = threadIdx.x + i * 256;
    const int p = d >> 1;
    // div = exp(2p * -ln(10000)/D); pe[2p]=sin(s*div), pe[2p+1]=cos(s*div)
    const double div = exp((double)(2 * p) * (-9.210340371976184 / 1024.0));
    const double ang = (double)s * div;
    const float pe = (d & 1) ? (float)cos(ang) : (float)sin(ang);
    xrow[d] = erow[d] * 32.0f + pe;     // sqrt(1024) = 32
  }
}

// ---- tiled SGEMM: C[M,N] = A[M,K] @ W[N,K]^T (+bias, opt ReLU) ------------
// 64x64 block tile, K-step 16, 256 threads, 4x4 micro-tile per thread.
__global__ __launch_bounds__(256) void gemm_bias_kernel(
    const float* __restrict__ A, const float* __restrict__ W,
    const float* __restrict__ bias, float* __restrict__ C,
    int M, int N, int K, int relu) {
  __shared__ float As[16][65];
  __shared__ float Ws[16][65];
  const int bm = blockIdx.y * 64;
  const int bn = blockIdx.x * 64;
  const int t  = threadIdx.x;
  const int tx = t & 15;          // n-tile
  const int ty = t >> 4;          // m-tile
  float acc[4][4] = {};
  for (int k0 = 0; k0 < K; k0 += 16) {
#pragma unroll
    for (int i = 0; i < 4; ++i) {
      const int idx = t + i * 256;        // 0..1023
      const int m  = idx >> 4;            // 0..63
      const int kk = idx & 15;
      As[kk][m] = A[(size_t)(bm + m) * K + k0 + kk];
      Ws[kk][m] = W[(size_t)(bn + m) * K + k0 + kk];
    }
    __syncthreads();
#pragma unroll
    for (int kk = 0; kk < 16; ++kk) {
      float a[4], b[4];
#pragma unroll
      for (int i = 0; i < 4; ++i) a[i] = As[kk][ty * 4 + i];
#pragma unroll
      for (int j = 0; j < 4; ++j) b[j] = Ws[kk][tx * 4 + j];
#pragma unroll
      for (int i = 0; i < 4; ++i)
#pragma unroll
        for (int j = 0; j < 4; ++j) acc[i][j] += a[i] * b[j];
    }
    __syncthreads();
  }
#pragma unroll
  for (int i = 0; i < 4; ++i) {
    const int m = bm + ty * 4 + i;
#pragma unroll
    for (int j = 0; j < 4; ++j) {
      const int n = bn + tx * 4 + j;
      float v = acc[i][j] + (bias ? bias[n] : 0.0f);
      if (relu) v = fmaxf(v, 0.0f);
      C[(size_t)m * N + n] = v;
    }
  }
}

// ---- causal attention: one block per (b, h, query row) --------------------
__global__ __launch_bounds__(256) void attn_kernel(
    const float* __restrict__ q, const float* __restrict__ k,
    const float* __restrict__ v, float* __restrict__ o) {
  const int bid = blockIdx.x;
  const int qs = bid & (kS - 1);
  const int bh = bid >> 10;
  const int h  = bh & (kH - 1);
  const int b  = bh >> 4;
  const int t  = threadIdx.x;

  __shared__ float sc[kS];
  __shared__ float qv[kDK];
  __shared__ float scratch[4];
  __shared__ float part[4][kDK];

  const size_t base = (size_t)(b * kS) * kD + (size_t)h * kDK;
  if (t < kDK) qv[t] = q[base + (size_t)qs * kD + t];
  __syncthreads();

  const int nk = qs + 1;                 // causal: keys 0..qs
  float lmax = -1e30f;
  for (int kk = t; kk < nk; kk += 256) {
    const float* krow = k + base + (size_t)kk * kD;
    float sacc = 0.f;
#pragma unroll
    for (int d2 = 0; d2 < kDK; ++d2) sacc += qv[d2] * krow[d2];
    sacc *= kScale;
    sc[kk] = sacc;
    lmax = fmaxf(lmax, sacc);
  }
  const float gmax = block_max256(lmax, scratch);

  float lsum = 0.f;
  for (int kk = t; kk < nk; kk += 256) {
    const float e = __expf(sc[kk] - gmax);
    sc[kk] = e;
    lsum += e;
  }
  const float gsum = block_sum256(lsum, scratch);  // barriers make sc[] visible
  const float inv  = 1.f / gsum;

  // O[d] = sum_k p[k] * V[k][d]; wave r handles k = r mod 4, lanes = d
  const int d = t & 63;
  const int r = t >> 6;
  float acc = 0.f;
  for (int kk = r; kk < nk; kk += 4) {
    acc += sc[kk] * v[base + (size_t)kk * kD + d];
  }
  part[r][d] = acc;
  __syncthreads();
  if (t < kDK) {
    const float oval = (part[0][t] + part[1][t] + part[2][t] + part[3][t]) * inv;
    o[base + (size_t)qs * kD + t] = oval;
  }
}

// ---- residual add + LayerNorm (in place on x); res may be null ------------
__global__ __launch_bounds__(256) void add_ln_kernel(
    float* __restrict__ x, const float* __restrict__ res,
    const float* __restrict__ g, const float* __restrict__ bta) {
  const int row = blockIdx.x;
  const int t   = threadIdx.x;
  __shared__ float scratch[4];
  float vals[4];
  float sum = 0.f;
  float* xrow = x + (size_t)row * kD;
#pragma unroll
  for (int i = 0; i < 4; ++i) {
    const int d = t + i * 256;
    float vv = xrow[d];
    if (res) vv += res[(size_t)row * kD + d];
    vals[i] = vv;
    sum += vv;
  }
  const float mean = block_sum256(sum, scratch) * (1.0f / kD);
  float vsum = 0.f;
#pragma unroll
  for (int i = 0; i < 4; ++i) {
    const float dd = vals[i] - mean;
    vsum += dd * dd;
  }
  const float var  = block_sum256(vsum, scratch) * (1.0f / kD);
  const float rstd = rsqrtf(var + kEps);
#pragma unroll
  for (int i = 0; i < 4; ++i) {
    const int d = t + i * 256;
    xrow[d] = (vals[i] - mean) * rstd * g[d] + bta[d];
  }
}

// ---------------------------------------------------------------------------
extern "C" void kernel_launch(void* const* d_in, const int* in_sizes, int n_in,
                              void* d_out, int out_size, void* d_ws, size_t ws_size,
                              hipStream_t stream) {
  const int*   ids   = (const int*)  d_in[0];
  const float* embed = (const float*)d_in[1];
  const float* Wq    = (const float*)d_in[2];
  const float* bq    = (const float*)d_in[3];
  const float* Wk    = (const float*)d_in[4];
  const float* bk    = (const float*)d_in[5];
  const float* Wv    = (const float*)d_in[6];
  const float* bv    = (const float*)d_in[7];
  const float* Wo    = (const float*)d_in[8];
  const float* bo    = (const float*)d_in[9];
  const float* ln1g  = (const float*)d_in[10];
  const float* ln1b  = (const float*)d_in[11];
  const float* W1    = (const float*)d_in[12];
  const float* b1    = (const float*)d_in[13];
  const float* W2    = (const float*)d_in[14];
  const float* b2    = (const float*)d_in[15];
  const float* ln2g  = (const float*)d_in[16];
  const float* ln2b  = (const float*)d_in[17];
  const float* lnfg  = (const float*)d_in[18];
  const float* lnfb  = (const float*)d_in[19];
  const float* headw = (const float*)d_in[20];

  // Workspace layout (floats):
  //   x  : kM*kD                      (residual stream, 8 MB)
  //   fb : kM*kF                      (32 MB; hosts q/k/v/o subregions, then ff1)
  //   pb : kM*kD                      (proj / ff2 output, 8 MB)
  float* x  = (float*)d_ws;
  float* fb = x + (size_t)kM * kD;
  float* qb = fb;
  float* kb = fb + (size_t)kM * kD;
  float* vb = fb + 2 * (size_t)kM * kD;
  float* ob = fb + 3 * (size_t)kM * kD;
  float* pb = fb + (size_t)kM * kF;

  const dim3 blk(256);
  const dim3 gD(kD / 64, kM / 64);     // 16 x 32
  const dim3 gF(kF / 64, kM / 64);     // 64 x 32
  const dim3 gV(kV / 64, kM / 64);     // 500 x 32

  embed_pe_kernel<<<kM, blk, 0, stream>>>(ids, embed, x);

  for (int l = 0; l < kL; ++l) {
    const size_t wOff = (size_t)l * kD * kD;
    gemm_bias_kernel<<<gD, blk, 0, stream>>>(x, Wq + wOff, bq + (size_t)l * kD, qb, kM, kD, kD, 0);
    gemm_bias_kernel<<<gD, blk, 0, stream>>>(x, Wk + wOff, bk + (size_t)l * kD, kb, kM, kD, kD, 0);
    gemm_bias_kernel<<<gD, blk, 0, stream>>>(x, Wv + wOff, bv + (size_t)l * kD, vb, kM, kD, kD, 0);
    attn_kernel<<<kB * kH * kS, blk, 0, stream>>>(qb, kb, vb, ob);
    gemm_bias_kernel<<<gD, blk, 0, stream>>>(ob, Wo + wOff, bo + (size_t)l * kD, pb, kM, kD, kD, 0);
    add_ln_kernel<<<kM, blk, 0, stream>>>(x, pb, ln1g + (size_t)l * kD, ln1b + (size_t)l * kD);
    gemm_bias_kernel<<<gF, blk, 0, stream>>>(x, W1 + (size_t)l * kF * kD, b1 + (size_t)l * kF, fb, kM, kF, kD, 1);
    gemm_bias_kernel<<<gD, blk, 0, stream>>>(fb, W2 + (size_t)l * kD * kF, b2 + (size_t)l * kD, pb, kM, kD, kF, 0);
    add_ln_kernel<<<kM, blk, 0, stream>>>(x, pb, ln2g + (size_t)l * kD, ln2b + (size_t)l * kD);
  }

  add_ln_kernel<<<kM, blk, 0, stream>>>(x, nullptr, lnfg, lnfb);
  gemm_bias_kernel<<<gV, blk, 0, stream>>>(x, headw, nullptr, (float*)d_out, kM, kV, kD, 0);
}

// Round 2
// 4987.201 us; speedup vs baseline: 2.3727x; 2.3727x over previous
//
#include <hip/hip_runtime.h>
#include <math.h>

// ---------------------------------------------------------------------------
// Round 2: bf16 MFMA GEMMs (m97 structure: 128x128 tile, BK=32,
// global_load_lds width-16, mfma_f32_16x16x32_bf16), qkv in [b][h][s][dk]
// layout for coalesced attention, 4-queries-per-block attention.
// Residual stream fp32; bf16 shadow (xb) for GEMM inputs.
// ---------------------------------------------------------------------------

namespace {
constexpr int kV  = 32000;
constexpr int kD  = 1024;
constexpr int kH  = 16;
constexpr int kL  = 4;
constexpr int kF  = 4096;
constexpr int kS  = 1024;
constexpr int kB  = 2;
constexpr int kDK = 64;
constexpr int kM  = kB * kS;   // 2048 rows
constexpr float kEps   = 1e-5f;
constexpr float kScale = 0.125f;   // 1/sqrt(DK)
}

using short8 = __attribute__((ext_vector_type(8))) short;
using f32x4  = __attribute__((ext_vector_type(4))) float;

__device__ __forceinline__ unsigned short f2bf(float f) {
  union { float f; unsigned int u; } x{f};
  const unsigned int r = x.u + 0x7fffu + ((x.u >> 16) & 1u);
  return (unsigned short)(r >> 16);
}

// async 16B global -> LDS (lane scatters to ldsbase + lane*16)
__device__ __forceinline__ void llds16(const void* g, void* l) {
  __builtin_amdgcn_global_load_lds(
      (const __attribute__((address_space(1))) unsigned int*)g,
      (__attribute__((address_space(3))) unsigned int*)l, 16, 0, 0);
}

// ---- block reductions (blockDim.x == 256 -> 4 waves of 64) ----------------
__device__ __forceinline__ float block_sum256(float v, float* scratch) {
#pragma unroll
  for (int off = 32; off > 0; off >>= 1) v += __shfl_down(v, off, 64);
  const int wid  = threadIdx.x >> 6;
  const int lane = threadIdx.x & 63;
  __syncthreads();
  if (lane == 0) scratch[wid] = v;
  __syncthreads();
  return scratch[0] + scratch[1] + scratch[2] + scratch[3];
}

__device__ __forceinline__ float block_max256(float v, float* scratch) {
#pragma unroll
  for (int off = 32; off > 0; off >>= 1) v = fmaxf(v, __shfl_down(v, off, 64));
  const int wid  = threadIdx.x >> 6;
  const int lane = threadIdx.x & 63;
  __syncthreads();
  if (lane == 0) scratch[wid] = v;
  __syncthreads();
  return fmaxf(fmaxf(scratch[0], scratch[1]), fmaxf(scratch[2], scratch[3]));
}

// ---- fp32 -> bf16 convert (vectorized x4) ---------------------------------
__global__ __launch_bounds__(256) void f2bf_kernel(const float* __restrict__ in,
                                                   unsigned short* __restrict__ out,
                                                   int n4) {
  const int i = blockIdx.x * 256 + threadIdx.x;
  if (i < n4) {
    const float4 v = ((const float4*)in)[i];
    ushort4 o;
    o.x = f2bf(v.x); o.y = f2bf(v.y); o.z = f2bf(v.z); o.w = f2bf(v.w);
    ((ushort4*)out)[i] = o;
  }
}

// ---- embedding + positional encoding (writes fp32 x and bf16 xb) ----------
__global__ __launch_bounds__(256) void embed_pe_kernel(
    const int* __restrict__ ids, const float* __restrict__ embed,
    float* __restrict__ x, unsigned short* __restrict__ xb) {
  const int row = blockIdx.x;           // b*kS + s
  const int s   = row & (kS - 1);
  const int id  = ids[row];
  const float* erow = embed + (size_t)id * kD;
#pragma unroll
  for (int i = 0; i < kD / 256; ++i) {
    const int d = threadIdx.x + i * 256;
    const int p = d >> 1;
    const double div = exp((double)(2 * p) * (-9.210340371976184 / 1024.0));
    const double ang = (double)s * div;
    const float pe = (d & 1) ? (float)cos(ang) : (float)sin(ang);
    const float v = erow[d] * 32.0f + pe;   // sqrt(1024)=32
    x[(size_t)row * kD + d]  = v;
    xb[(size_t)row * kD + d] = f2bf(v);
  }
}

// ---- bf16 MFMA GEMM core: C[M,N] = A[M,K] @ W[N,K]^T + bias ---------------
// MODE 0: fp32 row-major out (bias may be null)
// MODE 1: fp32 out in [b][h][s][dk] attention layout
// MODE 2: bf16 row-major out with ReLU
template <int MODE>
__device__ __forceinline__ void gemm_core(const unsigned short* __restrict__ A,
                                          const unsigned short* __restrict__ W,
                                          const float* __restrict__ bias,
                                          void* __restrict__ Cout,
                                          int M, int N, int K) {
  __shared__ __align__(16) unsigned short As[128 * 32];
  __shared__ __align__(16) unsigned short Ws[128 * 32];
  const int bm   = blockIdx.y * 128;
  const int bn   = blockIdx.x * 128;
  const int t    = threadIdx.x;
  const int lane = t & 63;
  const int w    = t >> 6;
  const int wm   = (w >> 1) * 64;
  const int wn   = (w & 1) * 64;
  const int l15  = lane & 15;
  const int quad = lane >> 4;

  f32x4 acc[4][4] = {};

  for (int k0 = 0; k0 < K; k0 += 32) {
    __syncthreads();
#pragma unroll
    for (int i = 0; i < 2; ++i) {
      const int e   = i * 256 + t;       // 0..511
      const int row = e >> 2;            // 0..127
      const int kc  = (e & 3) * 8;       // 0,8,16,24
      const int ldsoff = (i * 256 + w * 64) * 8;   // wave-uniform base (shorts)
      llds16(A + (size_t)(bm + row) * K + k0 + kc, &As[ldsoff]);
      llds16(W + (size_t)(bn + row) * K + k0 + kc, &Ws[ldsoff]);
    }
    __syncthreads();
    short8 af[4], bf[4];
#pragma unroll
    for (int i = 0; i < 4; ++i)
      af[i] = *(const short8*)&As[(wm + i * 16 + l15) * 32 + quad * 8];
#pragma unroll
    for (int j = 0; j < 4; ++j)
      bf[j] = *(const short8*)&Ws[(wn + j * 16 + l15) * 32 + quad * 8];
#pragma unroll
    for (int i = 0; i < 4; ++i)
#pragma unroll
      for (int j = 0; j < 4; ++j)
        acc[i][j] = __builtin_amdgcn_mfma_f32_16x16x32_bf16(af[i], bf[j], acc[i][j], 0, 0, 0);
  }

#pragma unroll
  for (int i = 0; i < 4; ++i) {
#pragma unroll
    for (int r = 0; r < 4; ++r) {
      const int m = bm + wm + i * 16 + quad * 4 + r;
#pragma unroll
      for (int j = 0; j < 4; ++j) {
        const int n = bn + wn + j * 16 + l15;
        float v = acc[i][j][r] + (bias ? bias[n] : 0.0f);
        if (MODE == 2) v = fmaxf(v, 0.0f);
        if (MODE == 0) {
          ((float*)Cout)[(size_t)m * N + n] = v;
        } else if (MODE == 1) {
          const int b = m >> 10, s = m & 1023;
          const int h = n >> 6,  dk = n & 63;
          ((float*)Cout)[((((size_t)b * kH + h) << 10) + s) * kDK + dk] = v;
        } else {
          ((unsigned short*)Cout)[(size_t)m * N + n] = f2bf(v);
        }
      }
    }
  }
}

__global__ __launch_bounds__(256) void gemm_qkv_kernel(
    const unsigned short* __restrict__ A,
    const unsigned short* __restrict__ w0, const unsigned short* __restrict__ w1,
    const unsigned short* __restrict__ w2,
    const float* __restrict__ b0, const float* __restrict__ b1,
    const float* __restrict__ b2,
    float* __restrict__ o0, float* __restrict__ o1, float* __restrict__ o2) {
  const int z = blockIdx.z;
  const unsigned short* W = (z == 0) ? w0 : (z == 1) ? w1 : w2;
  const float* bias       = (z == 0) ? b0 : (z == 1) ? b1 : b2;
  float* O                = (z == 0) ? o0 : (z == 1) ? o1 : o2;
  gemm_core<1>(A, W, bias, O, kM, kD, kD);
}

__global__ __launch_bounds__(256) void gemm_f32_kernel(
    const unsigned short* __restrict__ A, const unsigned short* __restrict__ W,
    const float* __restrict__ bias, float* __restrict__ C, int M, int N, int K) {
  gemm_core<0>(A, W, bias, C, M, N, K);
}

__global__ __launch_bounds__(256) void gemm_bf16relu_kernel(
    const unsigned short* __restrict__ A, const unsigned short* __restrict__ W,
    const float* __restrict__ bias, unsigned short* __restrict__ C,
    int M, int N, int K) {
  gemm_core<2>(A, W, bias, C, M, N, K);
}

// ---- causal attention: one block per (b, h, 4 queries) --------------------
// q,k,v in [b][h][s][dk] fp32; output ob bf16 row-major [M][D].
__global__ __launch_bounds__(256) void attn_kernel(
    const float* __restrict__ q, const float* __restrict__ k,
    const float* __restrict__ v, unsigned short* __restrict__ ob) {
  const int bid = blockIdx.x;
  const int qt  = bid & (kS / 4 - 1);     // 0..255
  const int h   = (bid >> 8) & (kH - 1);
  const int b   = bid >> 12;
  const int q0  = qt * 4;
  const int t   = threadIdx.x;

  __shared__ float qv[4][kDK];
  __shared__ float sc[4][kS];
  __shared__ float scratch[4];
  __shared__ float part[4][4][kDK];

  const size_t base = ((size_t)(b * kH + h)) * kS * kDK;
  if (t < 256) {
    const int j = t >> 6, d = t & 63;
    qv[j][d] = q[base + (size_t)(q0 + j) * kDK + d];
  }
  __syncthreads();

  const int nkmax = q0 + 4;               // keys 0..q0+3 cover all 4 queries
  float lm[4] = {-1e30f, -1e30f, -1e30f, -1e30f};
  for (int kk = t; kk < nkmax; kk += 256) {
    const float4* kr = (const float4*)(k + base + (size_t)kk * kDK);
    float sj[4] = {0.f, 0.f, 0.f, 0.f};
#pragma unroll
    for (int c = 0; c < 16; ++c) {
      const float4 kv4 = kr[c];
#pragma unroll
      for (int j = 0; j < 4; ++j) {
        const float4 qj = ((const float4*)qv[j])[c];
        sj[j] += kv4.x * qj.x + kv4.y * qj.y + kv4.z * qj.z + kv4.w * qj.w;
      }
    }
#pragma unroll
    for (int j = 0; j < 4; ++j) {
      const float val = (kk <= q0 + j) ? sj[j] * kScale : -1e30f;
      sc[j][kk] = val;
      lm[j] = fmaxf(lm[j], val);
    }
  }
  float gm[4];
#pragma unroll
  for (int j = 0; j < 4; ++j) gm[j] = block_max256(lm[j], scratch);

  float ls[4] = {0.f, 0.f, 0.f, 0.f};
  for (int kk = t; kk < nkmax; kk += 256) {
#pragma unroll
    for (int j = 0; j < 4; ++j) {
      const float e = __expf(sc[j][kk] - gm[j]);
      sc[j][kk] = e;
      ls[j] += e;
    }
  }
  float inv[4];
#pragma unroll
  for (int j = 0; j < 4; ++j) inv[j] = 1.0f / block_sum256(ls[j], scratch);

  // O[j][d] = sum_k p[j][k] * V[k][d]; wave r handles k = r mod 4
  const int d = t & 63;
  const int r = t >> 6;
  float accj[4] = {0.f, 0.f, 0.f, 0.f};
  for (int kk = r; kk < nkmax; kk += 4) {
    const float vv = v[base + (size_t)kk * kDK + d];
#pragma unroll
    for (int j = 0; j < 4; ++j) accj[j] += sc[j][kk] * vv;
  }
#pragma unroll
  for (int j = 0; j < 4; ++j) part[r][j][d] = accj[j];
  __syncthreads();
  {
    const int j = t >> 6;
    const float o = (part[0][j][d] + part[1][j][d] + part[2][j][d] + part[3][j][d]) * inv[j];
    ob[((size_t)(b * kS + q0 + j)) * kD + h * kDK + d] = f2bf(o);
  }
}

// ---- residual add + LayerNorm; writes fp32 x and bf16 xb ------------------
__global__ __launch_bounds__(256) void add_ln_kernel(
    float* __restrict__ x, const float* __restrict__ res,
    const float* __restrict__ g, const float* __restrict__ bta,
    unsigned short* __restrict__ xb) {
  const int row = blockIdx.x;
  const int t   = threadIdx.x;
  __shared__ float scratch[4];
  float vals[4];
  float sum = 0.f;
  float* xrow = x + (size_t)row * kD;
#pragma unroll
  for (int i = 0; i < 4; ++i) {
    const int d = t + i * 256;
    float vv = xrow[d];
    if (res) vv += res[(size_t)row * kD + d];
    vals[i] = vv;
    sum += vv;
  }
  const float mean = block_sum256(sum, scratch) * (1.0f / kD);
  float vsum = 0.f;
#pragma unroll
  for (int i = 0; i < 4; ++i) {
    const float dd = vals[i] - mean;
    vsum += dd * dd;
  }
  const float var  = block_sum256(vsum, scratch) * (1.0f / kD);
  const float rstd = rsqrtf(var + kEps);
#pragma unroll
  for (int i = 0; i < 4; ++i) {
    const int d = t + i * 256;
    const float o = (vals[i] - mean) * rstd * g[d] + bta[d];
    xrow[d] = o;
    xb[(size_t)row * kD + d] = f2bf(o);
  }
}

// ---------------------------------------------------------------------------
extern "C" void kernel_launch(void* const* d_in, const int* in_sizes, int n_in,
                              void* d_out, int out_size, void* d_ws, size_t ws_size,
                              hipStream_t stream) {
  const int*   ids   = (const int*)  d_in[0];
  const float* embed = (const float*)d_in[1];
  const float* Wq    = (const float*)d_in[2];
  const float* bq    = (const float*)d_in[3];
  const float* Wk    = (const float*)d_in[4];
  const float* bk    = (const float*)d_in[5];
  const float* Wv    = (const float*)d_in[6];
  const float* bv    = (const float*)d_in[7];
  const float* Wo    = (const float*)d_in[8];
  const float* bo    = (const float*)d_in[9];
  const float* ln1g  = (const float*)d_in[10];
  const float* ln1b  = (const float*)d_in[11];
  const float* W1    = (const float*)d_in[12];
  const float* b1    = (const float*)d_in[13];
  const float* W2    = (const float*)d_in[14];
  const float* b2    = (const float*)d_in[15];
  const float* ln2g  = (const float*)d_in[16];
  const float* ln2b  = (const float*)d_in[17];
  const float* lnfg  = (const float*)d_in[18];
  const float* lnfb  = (const float*)d_in[19];
  const float* headw = (const float*)d_in[20];

  // Workspace layout (bytes):
  char* ws = (char*)d_ws;
  float*          x    = (float*)          (ws);              // 8 MB
  unsigned short* xb   = (unsigned short*) (ws + 8388608);    // 4 MB
  float*          qb   = (float*)          (ws + 12582912);   // 8 MB  [b][h][s][dk]
  float*          kb   = (float*)          (ws + 20971520);   // 8 MB
  float*          vb   = (float*)          (ws + 29360128);   // 8 MB
  unsigned short* ob   = (unsigned short*) (ws + 37748736);   // 4 MB  [M][D] bf16
  unsigned short* ff1b = (unsigned short*) (ws + 41943040);   // 16 MB [M][F] bf16
  float*          pb   = (float*)          (ws + 58720256);   // 8 MB  [M][D] f32
  unsigned short* wbuf = (unsigned short*) (ws + 67108864);   // 62.5 MB bf16 weights
  // wbuf element offsets: wq 0, wk 1M, wv 2M, wo 3M, w1 4M..8M, w2 8M..12M
  // head reuses wbuf[0 .. 32.768M)

  const dim3 blk(256);
  embed_pe_kernel<<<kM, blk, 0, stream>>>(ids, embed, x, xb);

  for (int l = 0; l < kL; ++l) {
    const size_t oD = (size_t)l * kD * kD;     // 1M
    const size_t oF = (size_t)l * kF * kD;     // 4M
    // convert this layer's weights to bf16
    f2bf_kernel<<<1024, blk, 0, stream>>>(Wq + oD, wbuf,            262144);
    f2bf_kernel<<<1024, blk, 0, stream>>>(Wk + oD, wbuf + 1048576,  262144);
    f2bf_kernel<<<1024, blk, 0, stream>>>(Wv + oD, wbuf + 2097152,  262144);
    f2bf_kernel<<<1024, blk, 0, stream>>>(Wo + oD, wbuf + 3145728,  262144);
    f2bf_kernel<<<4096, blk, 0, stream>>>(W1 + oF, wbuf + 4194304, 1048576);
    f2bf_kernel<<<4096, blk, 0, stream>>>(W2 + oF, wbuf + 8388608, 1048576);

    gemm_qkv_kernel<<<dim3(8, 16, 3), blk, 0, stream>>>(
        xb, wbuf, wbuf + 1048576, wbuf + 2097152,
        bq + (size_t)l * kD, bk + (size_t)l * kD, bv + (size_t)l * kD,
        qb, kb, vb);
    attn_kernel<<<kB * kH * (kS / 4), blk, 0, stream>>>(qb, kb, vb, ob);
    gemm_f32_kernel<<<dim3(8, 16), blk, 0, stream>>>(
        ob, wbuf + 3145728, bo + (size_t)l * kD, pb, kM, kD, kD);
    add_ln_kernel<<<kM, blk, 0, stream>>>(x, pb, ln1g + (size_t)l * kD, ln1b + (size_t)l * kD, xb);
    gemm_bf16relu_kernel<<<dim3(32, 16), blk, 0, stream>>>(
        xb, wbuf + 4194304, b1 + (size_t)l * kF, ff1b, kM, kF, kD);
    gemm_f32_kernel<<<dim3(8, 16), blk, 0, stream>>>(
        ff1b, wbuf + 8388608, b2 + (size_t)l * kD, pb, kM, kD, kF);
    add_ln_kernel<<<kM, blk, 0, stream>>>(x, pb, ln2g + (size_t)l * kD, ln2b + (size_t)l * kD, xb);
  }

  add_ln_kernel<<<kM, blk, 0, stream>>>(x, nullptr, lnfg, lnfb, xb);
  f2bf_kernel<<<32000, blk, 0, stream>>>(headw, wbuf, 8192000);
  gemm_f32_kernel<<<dim3(250, 16), blk, 0, stream>>>(
      xb, wbuf, nullptr, (float*)d_out, kM, kV, kD);
}